// Round 4
// baseline (2335.976 us; speedup 1.0000x reference)
//
#include <hip/hip_runtime.h>
#include <hip/hip_bf16.h>

#define Bdim 256
#define Tdim 256
#define Idim 256
#define Hdim 1024
#define KDIM 1280   // I + H
#define NP   4096   // 4*H, gate-interleaved: n' = 4*hu + gate

typedef __attribute__((ext_vector_type(8)))  short short8;
typedef __attribute__((ext_vector_type(4)))  short short4v;
typedef __attribute__((ext_vector_type(16))) float f32x16;
typedef unsigned long long u64;

__device__ __forceinline__ short f2bf(float f) {
  unsigned u = __builtin_bit_cast(unsigned, f);
  unsigned r = (u + 0x7FFFu + ((u >> 16) & 1u)) >> 16;   // RNE
  return (short)r;
}
__device__ __forceinline__ float bf2f(short s) {
  unsigned u = ((unsigned)(unsigned short)s) << 16;
  return __builtin_bit_cast(float, u);
}

// ---------------- setup: Wt[n'][k] = bf16(W[k][(n'&3)*H + (n'>>2)]) ----------------
__global__ void setup_wt_kernel(const float* __restrict__ Wx,
                                const float* __restrict__ Wh,
                                short* __restrict__ Wt) {
  __shared__ float tile[64 * 65];
  const int nb = blockIdx.x, kb = blockIdx.y;
  const int tid = threadIdx.x;
#pragma unroll
  for (int i = 0; i < 16; ++i) {
    int idx = i * 256 + tid;
    int kr = idx >> 6, nc = idx & 63;
    int kglob = kb * 64 + kr;
    int np = nb * 64 + nc;
    int col = ((np & 3) << 10) | (np >> 2);
    float v = (kglob < Idim) ? Wx[(size_t)kglob * NP + col]
                             : Wh[(size_t)(kglob - Idim) * NP + col];
    tile[kr * 65 + nc] = v;
  }
  __syncthreads();
#pragma unroll
  for (int i = 0; i < 16; ++i) {
    int idx = i * 256 + tid;
    int nr = idx >> 6, kc = idx & 63;
    Wt[(size_t)(nb * 64 + nr) * KDIM + kb * 64 + kc] = f2bf(tile[kc * 65 + nr]);
  }
}

// ---------------- setup: state init + bias reorder + barrier zero ----------------
__global__ void setup_state_kernel(const float* __restrict__ h0,
                                   const float* __restrict__ c0,
                                   const float* __restrict__ b,
                                   short* __restrict__ Uh0,
                                   float* __restrict__ c_state,
                                   float* __restrict__ bp,
                                   unsigned* __restrict__ bar) {
  if (blockIdx.x == 1041) {
    if (threadIdx.x < 256) bar[threadIdx.x] = 0u;
    return;
  }
  int idx = blockIdx.x * 256 + threadIdx.x;
  if (blockIdx.x < 1024) {          // B*H = 262144 state elems
    Uh0[idx] = f2bf(h0[idx]);
    c_state[idx] = c0[idx];
  } else if (blockIdx.x < 1040) {
    int j = idx - 1024 * 256;
    if (j < NP) bp[j] = b[((j & 3) << 10) | (j >> 2)];
  }
}

// ---------------- persistent fused LSTM ----------------
// 256 blocks x 512 threads (8 waves). block = (m = blockIdx&7 batch-tile of 32
// rows, ng = blockIdx>>3 hu-group of 32). wave = (ntl = wave&3 n' tile,
// kh = wave>>2 K half). Weights in 160 VGPR/wave (40 x short8), pinned.
// Per-wave K split: x part kh*128..+128 (8 MFMAs, OFF the critical path —
// computed for step t+1 during step t's barrier window), h part kh*512..+512
// (32 MFMAs, on-path). c state lives in 2 VGPR/thread for the whole sequence.
// Cross-block h + flags via relaxed agent-scope atomics only, no fences.
__global__ __launch_bounds__(512) __attribute__((amdgpu_waves_per_eu(2, 2)))
void lstm_persistent(
    const float* __restrict__ xin,    // (B,T,I) fp32
    const short* __restrict__ Wt,     // (NP, KDIM) bf16
    const float* __restrict__ bp,     // (NP) fp32 reordered
    short* __restrict__ Uh0,          // (B,H) bf16 h state buf 0
    short* __restrict__ Uh1,          // (B,H) bf16 h state buf 1
    float* __restrict__ out,          // (B,T,H) fp32
    float* __restrict__ c_state,      // (B,H) fp32 (aliases cN output)
    float* __restrict__ hN,           // (B,H) fp32 final h
    unsigned* __restrict__ bar) {     // flags: bar[m*32 + ng] = steps completed
  __shared__ __align__(16) short Asx[32 * 256];       // 16 KB, swizzled
  __shared__ __align__(16) short Ash[32 * 1024];      // 64 KB, swizzled
  __shared__ __align__(16) float Gred[2][32][132];    // 33.8 KB

  const int tid  = threadIdx.x;
  const int lane = tid & 63;
  const int wave = tid >> 6;        // 0..7
  const int ntl  = wave & 3;
  const int kh   = wave >> 2;
  const int m    = blockIdx.x & 7;
  const int ng   = blockIdx.x >> 3;
  const int bm0  = m * 32;
  const int n0   = ng * 128 + ntl * 32;
  const int lrow = lane & 31;
  const int koff = (lane >> 5) << 3;    // element offset within 16-wide k

  // ---- one-time: weights into registers (40 x short8 = 160 VGPR) ----
  // Wreg[0..7]  : x part, k = kh*128 + j*16 + koff
  // Wreg[8..39] : h part, k = 256 + kh*512 + j*16 + koff
  short8 Wreg[40];
  {
    const short* wr = Wt + (size_t)(n0 + lrow) * KDIM + koff;
#pragma unroll
    for (int j = 0; j < 8; ++j)  Wreg[j]     = *(const short8*)(wr + kh * 128 + j * 16);
#pragma unroll
    for (int j = 0; j < 32; ++j) Wreg[8 + j] = *(const short8*)(wr + 256 + kh * 512 + j * 16);
  }
#pragma unroll
  for (int ks = 0; ks < 40; ++ks) asm volatile("" : "+v"(Wreg[ks]));

  // A-fragment read bases (byte offsets, XOR swizzle by (row&15)<<4)
  const int axor = (lrow & 15) << 4;
  const int xfb  = lrow * 512  + kh * 256  + ((lane >> 5) << 4);
  const int hfb  = lrow * 2048 + kh * 1024 + ((lane >> 5) << 4);

  // x staging: thread -> (row xr, 16 cols at xc)
  const int xr = tid >> 4;
  const int xc = (tid & 15) << 4;
  const float* xp_base = xin + (size_t)(bm0 + xr) * (Tdim * Idim) + xc;
  const int xw0 = xr * 512 + xc * 2;
  const int xwx = (xr & 15) << 4;

  // h staging: thread owns rows row0+4i, fixed col c8
  const int row0 = tid >> 7;
  const int c8   = (tid & 127) << 3;

  // epilogue: thread owns (row erow, hu pair 2ep, 2ep+1) — fixed for all t
  const int erow = tid >> 4;
  const int ep   = tid & 15;
  const float4 bb0 = ((const float4*)bp)[ng * 32 + 2 * ep];
  const float4 bb1 = ((const float4*)bp)[ng * 32 + 2 * ep + 1];
  const int hu0 = ng * 32 + 2 * ep;
  const size_t cidx = (size_t)(bm0 + erow) * Hdim + hu0;
  float2 cReg = *(const float2*)&c_state[cidx];   // c lives in regs for all t
  float2 hLast = make_float2(0.f, 0.f);

  unsigned* flags = bar + m * 32;

  // ---- prologue: stage x_0, acc = x_0 partial; issue x_1 prefetch ----
  {
    const float* p = xp_base;   // t = 0
    float4 a0 = *(const float4*)p,     a1 = *(const float4*)(p + 4);
    float4 a2 = *(const float4*)(p + 8), a3 = *(const float4*)(p + 12);
    short8 v0, v1;
    v0[0]=f2bf(a0.x); v0[1]=f2bf(a0.y); v0[2]=f2bf(a0.z); v0[3]=f2bf(a0.w);
    v0[4]=f2bf(a1.x); v0[5]=f2bf(a1.y); v0[6]=f2bf(a1.z); v0[7]=f2bf(a1.w);
    v1[0]=f2bf(a2.x); v1[1]=f2bf(a2.y); v1[2]=f2bf(a2.z); v1[3]=f2bf(a2.w);
    v1[4]=f2bf(a3.x); v1[5]=f2bf(a3.y); v1[6]=f2bf(a3.z); v1[7]=f2bf(a3.w);
    *(short8*)((char*)Asx + (xw0 ^ xwx)) = v0;
    *(short8*)((char*)Asx + ((xw0 + 16) ^ xwx)) = v1;
  }
  float4 rX0, rX1, rX2, rX3;   // x prefetch pipeline regs (x_{t+2})
  {
    const float* p = xp_base + Idim;   // x_1
    rX0 = *(const float4*)p;      rX1 = *(const float4*)(p + 4);
    rX2 = *(const float4*)(p + 8); rX3 = *(const float4*)(p + 12);
  }
  __syncthreads();
  f32x16 acc;
#pragma unroll
  for (int i = 0; i < 16; ++i) acc[i] = 0.f;
#pragma unroll
  for (int ks = 0; ks < 8; ++ks) {
    short8 a = *(const short8*)((char*)Asx + ((xfb + ks * 32) ^ axor));
    acc = __builtin_amdgcn_mfma_f32_32x32x16_bf16(a, Wreg[ks], acc, 0, 0, 0);
  }
  __syncthreads();   // prologue Asx reads done before t=0 overwrites it

  for (int t = 0; t < Tdim; ++t) {
    const short* UhR = (t & 1) ? Uh1 : Uh0;
    short* UhW = (t & 1) ? Uh0 : Uh1;

    // ---- top staging: convert x_{t+1} (regs) -> Asx; issue x_{t+2} loads ----
    if (t < Tdim - 1) {
      short8 v0, v1;
      v0[0]=f2bf(rX0.x); v0[1]=f2bf(rX0.y); v0[2]=f2bf(rX0.z); v0[3]=f2bf(rX0.w);
      v0[4]=f2bf(rX1.x); v0[5]=f2bf(rX1.y); v0[6]=f2bf(rX1.z); v0[7]=f2bf(rX1.w);
      v1[0]=f2bf(rX2.x); v1[1]=f2bf(rX2.y); v1[2]=f2bf(rX2.z); v1[3]=f2bf(rX2.w);
      v1[4]=f2bf(rX3.x); v1[5]=f2bf(rX3.y); v1[6]=f2bf(rX3.z); v1[7]=f2bf(rX3.w);
      *(short8*)((char*)Asx + (xw0 ^ xwx)) = v0;
      *(short8*)((char*)Asx + ((xw0 + 16) ^ xwx)) = v1;
    }
    if (t < Tdim - 2) {
      const float* p = xp_base + (size_t)(t + 2) * Idim;
      rX0 = *(const float4*)p;       rX1 = *(const float4*)(p + 4);
      rX2 = *(const float4*)(p + 8); rX3 = *(const float4*)(p + 12);
    }

    // ---- stage h_t (coherent) into Ash ----
    {
      const short* hb = UhR + (size_t)(bm0 + row0) * Hdim + c8;
#pragma unroll
      for (int i = 0; i < 8; ++i) {
        const short* hp = hb + (size_t)(4 * i) * Hdim;
        u64 lo = __hip_atomic_load((const u64*)hp, __ATOMIC_RELAXED,
                                   __HIP_MEMORY_SCOPE_AGENT);
        u64 hi = __hip_atomic_load((const u64*)(hp + 4), __ATOMIC_RELAXED,
                                   __HIP_MEMORY_SCOPE_AGENT);
        short4v vlo = __builtin_bit_cast(short4v, lo);
        short4v vhi = __builtin_bit_cast(short4v, hi);
        if (t > 0 && c8 == 0) {
          // oscillator state update on h cols 0,1 (transient, gate-input only)
          float x0 = bf2f(vlo[0]), x1 = bf2f(vlo[1]);
          vlo[0] = f2bf(x0 + 0.05f * (1.5f * x0 + (1.0f / 1.5f) * x1));
          vlo[1] = f2bf(x1 - 0.05f * 1.5f * x0);
        }
        int row = row0 + 4 * i;
        char* dst = (char*)Ash + (((row * 2048) + (c8 << 1)) ^ ((row & 15) << 4));
        *(short4v*)dst = vlo;
        *(short4v*)(dst + 8) = vhi;
      }
    }
    __syncthreads();

    // ---- h-part MFMA: acc (carries x_t partial) += h * Wh-half ----
#pragma unroll
    for (int ks = 0; ks < 32; ++ks) {
      short8 a = *(const short8*)((char*)Ash + ((hfb + ks * 32) ^ axor));
      acc = __builtin_amdgcn_mfma_f32_32x32x16_bf16(a, Wreg[8 + ks], acc, 0, 0, 0);
    }

    // ---- K-half partials to LDS ----
    {
      const int col = lane & 31, half = lane >> 5;
#pragma unroll
      for (int r = 0; r < 16; ++r) {
        int rl = (r & 3) + 8 * (r >> 2) + 4 * half;
        Gred[kh][rl][ntl * 32 + col] = acc[r];
      }
    }
    __syncthreads();

    // ---- fused LSTM epilogue: 2 adjacent cells per thread, c in regs ----
    {
      float4 a0 = *(const float4*)&Gred[0][erow][8 * ep];
      float4 a1 = *(const float4*)&Gred[0][erow][8 * ep + 4];
      float4 d0 = *(const float4*)&Gred[1][erow][8 * ep];
      float4 d1 = *(const float4*)&Gred[1][erow][8 * ep + 4];
      float gx0 = a0.x + d0.x + bb0.x, gy0 = a0.y + d0.y + bb0.y;
      float gz0 = a0.z + d0.z + bb0.z, gw0 = a0.w + d0.w + bb0.w;
      float gx1 = a1.x + d1.x + bb1.x, gy1 = a1.y + d1.y + bb1.y;
      float gz1 = a1.z + d1.z + bb1.z, gw1 = a1.w + d1.w + bb1.w;
      float iv0 = 1.0f / (1.0f + __expf(-gx0));
      float fv0 = 1.0f / (1.0f + __expf(-gy0));
      float gg0 = 2.0f / (1.0f + __expf(-2.0f * gz0)) - 1.0f;
      float ov0 = 1.0f / (1.0f + __expf(-gw0));
      float iv1 = 1.0f / (1.0f + __expf(-gx1));
      float fv1 = 1.0f / (1.0f + __expf(-gy1));
      float gg1 = 2.0f / (1.0f + __expf(-2.0f * gz1)) - 1.0f;
      float ov1 = 1.0f / (1.0f + __expf(-gw1));
      float cn0 = fv0 * cReg.x + iv0 * gg0;
      float cn1 = fv1 * cReg.y + iv1 * gg1;
      cReg = make_float2(cn0, cn1);
      float hv0 = ov0 * (2.0f / (1.0f + __expf(-2.0f * cn0)) - 1.0f);
      float hv1 = ov1 * (2.0f / (1.0f + __expf(-2.0f * cn1)) - 1.0f);
      // h-state store FIRST (it gates the flag), then bulk out store
      unsigned hpk = (unsigned)(unsigned short)f2bf(hv0) |
                     ((unsigned)(unsigned short)f2bf(hv1) << 16);
      __hip_atomic_store((unsigned*)&UhW[cidx], hpk, __ATOMIC_RELAXED,
                         __HIP_MEMORY_SCOPE_AGENT);
      *(float2*)&out[(size_t)(bm0 + erow) * (Tdim * Hdim) + (size_t)t * Hdim + hu0] =
          make_float2(hv0, hv1);
      hLast = make_float2(hv0, hv1);
    }

    if (t < Tdim - 1) {
      // ---- x-part MFMA for step t+1 (overlaps h-store latency) ----
#pragma unroll
      for (int i = 0; i < 16; ++i) acc[i] = 0.f;
#pragma unroll
      for (int ks = 0; ks < 8; ++ks) {
        short8 a = *(const short8*)((char*)Asx + ((xfb + ks * 32) ^ axor));
        acc = __builtin_amdgcn_mfma_f32_32x32x16_bf16(a, Wreg[ks], acc, 0, 0, 0);
      }
      // ---- per-m-group barrier (32 blocks), monotonic flags, no fences ----
      asm volatile("s_waitcnt vmcnt(0)" ::: "memory");
      __syncthreads();
      if (wave == 0) {
        if (lane == 0)
          __hip_atomic_store(&flags[ng], (unsigned)(t + 1), __ATOMIC_RELAXED,
                             __HIP_MEMORY_SCOPE_AGENT);
        const unsigned tgt = (unsigned)(t + 1);
        for (;;) {
          unsigned v = __hip_atomic_load(&flags[lane & 31], __ATOMIC_RELAXED,
                                         __HIP_MEMORY_SCOPE_AGENT);
          if (__all((int)(v >= tgt))) break;
          __builtin_amdgcn_s_sleep(1);
        }
      }
      __syncthreads();
    }
  }

  // ---- final c and hN from registers ----
  *(float2*)&c_state[cidx] = cReg;
  *(float2*)&hN[cidx] = hLast;
}

extern "C" void kernel_launch(void* const* d_in, const int* in_sizes, int n_in,
                              void* d_out, int out_size, void* d_ws, size_t ws_size,
                              hipStream_t stream) {
  const float* xin = (const float*)d_in[0];
  const float* h0  = (const float*)d_in[1];
  const float* c0  = (const float*)d_in[2];
  const float* Wx  = (const float*)d_in[3];
  const float* Wh  = (const float*)d_in[4];
  const float* b   = (const float*)d_in[5];
  float* out = (float*)d_out;

  // workspace layout (~11.6 MB): Wt | Uh0 | Uh1 | bp | bar
  char* ws = (char*)d_ws;
  short* Wt  = (short*)ws;                                   // 4096*1280*2 = 10485760
  short* Uh0 = (short*)(ws + 10485760);                      // 524288
  short* Uh1 = (short*)(ws + 10485760 + 524288);             // 524288
  float* bp  = (float*)(ws + 10485760 + 1048576);            // 16384
  unsigned* bar = (unsigned*)(ws + 10485760 + 1048576 + 16384);  // 1024 B

  float* hN      = out + (size_t)Bdim * Tdim * Hdim;
  float* c_state = hN + (size_t)Bdim * Hdim;   // cN region doubles as running c

  setup_wt_kernel<<<dim3(64, 20), 256, 0, stream>>>(Wx, Wh, Wt);
  setup_state_kernel<<<1042, 256, 0, stream>>>(h0, c0, b, Uh0, c_state, bp, bar);

  void* args[] = {(void*)&xin, (void*)&Wt, (void*)&bp, (void*)&Uh0, (void*)&Uh1,
                  (void*)&out, (void*)&c_state, (void*)&hN, (void*)&bar};
  hipLaunchCooperativeKernel((const void*)lstm_persistent, dim3(256), dim3(512),
                             args, 0, stream);
}